// Round 7
// baseline (886.058 us; speedup 1.0000x reference)
//
#include <hip/hip_runtime.h>
#include <hip/hip_bf16.h>

typedef unsigned short u16;
typedef __attribute__((ext_vector_type(4))) unsigned short u16x4;
typedef __attribute__((ext_vector_type(8))) unsigned short u16x8;
typedef __attribute__((ext_vector_type(8))) short bf16x8;
typedef __attribute__((ext_vector_type(4))) float f32x4;

__device__ __forceinline__ u16 f2bs(float f) {
    union { float f; unsigned int u; } x; x.f = f;
    unsigned int r = x.u + 0x7FFFu + ((x.u >> 16) & 1u);   // RNE
    return (u16)(r >> 16);
}
__device__ __forceinline__ float bs2f(u16 u) {
    union { unsigned int u; float f; } x; x.u = ((unsigned int)u) << 16; return x.f;
}
__device__ __forceinline__ float lrelu(float e) { return e >= 0.f ? e : 0.2f * e; }

// ---------------- CSR build ----------------
__global__ void deg_kernel(const int* __restrict__ dst, int* __restrict__ deg, int E) {
    int i = blockIdx.x * 256 + threadIdx.x;
    if (i < E) atomicAdd(&deg[dst[i]], 1);
}

__global__ __launch_bounds__(1024) void scan_local(const int* __restrict__ deg,
        int* __restrict__ ptr, int* __restrict__ bsum, int N) {
    __shared__ int wsum[16];
    const int t = threadIdx.x, i = blockIdx.x * 1024 + t;
    const int lane = t & 63, w = t >> 6;
    int v = (i < N) ? deg[i] : 0;
    int x = v;
    #pragma unroll
    for (int off = 1; off < 64; off <<= 1) { int y = __shfl_up(x, off); if (lane >= off) x += y; }
    if (lane == 63) wsum[w] = x;
    __syncthreads();
    if (w == 0) {
        int s = (lane < 16) ? wsum[lane] : 0;
        #pragma unroll
        for (int off = 1; off < 16; off <<= 1) { int y = __shfl_up(s, off); if (lane >= off) s += y; }
        if (lane < 16) wsum[lane] = s;
    }
    __syncthreads();
    int incl = x + (w > 0 ? wsum[w - 1] : 0);
    if (i < N) ptr[i + 1] = incl;
    if (t == 0) bsum[blockIdx.x] = wsum[15];
}

__global__ __launch_bounds__(64) void scan_carry(int* __restrict__ bsum, int nb) {
    int t = threadIdx.x;
    int v = (t < nb) ? bsum[t] : 0;
    int x = v;
    #pragma unroll
    for (int off = 1; off < 64; off <<= 1) { int y = __shfl_up(x, off); if (t >= off) x += y; }
    if (t < nb) bsum[t] = x - v;
}

__global__ __launch_bounds__(1024) void scan_final(const int* __restrict__ deg,
        int* __restrict__ ptr, int* __restrict__ cur, const int* __restrict__ bsum, int N) {
    int i = blockIdx.x * 1024 + threadIdx.x;
    if (i == 0) ptr[0] = 0;
    if (i < N) {
        int p = ptr[i + 1] + bsum[blockIdx.x];
        ptr[i + 1] = p;
        cur[i] = p - deg[i];
    }
}

// also records dst and graph-of-dst per CSR slot
__global__ void fill_kernel(const int* __restrict__ src, const int* __restrict__ dst,
        const int* __restrict__ batch, int* __restrict__ cur,
        int* __restrict__ csr, int* __restrict__ dstA, int* __restrict__ gedge, int E) {
    int i = blockIdx.x * 256 + threadIdx.x;
    if (i < E) {
        int d = dst[i];
        int p = atomicAdd(&cur[d], 1);
        csr[p] = src[i];
        dstA[p] = d;
        gedge[p] = batch[d];
    }
}

// ---------------- weight transpose ----------------
__global__ void transpose_w(const float* __restrict__ W, u16* __restrict__ Wt,
        int K, int Nn, int KT) {
    int idx = blockIdx.x * 256 + threadIdx.x;
    if (idx >= Nn * KT) return;
    int n = idx / KT, k = idx - n * KT;
    Wt[(size_t)n * KT + k] = (k < K) ? f2bs(W[(size_t)k * Nn + n]) : (u16)0;
}

__global__ __launch_bounds__(256) void conv_x(const float* __restrict__ x, u16* __restrict__ xbf) {
    int r = blockIdx.x, t = threadIdx.x;
    const float* row = x + (size_t)r * 775;
    u16* orow = xbf + (size_t)r * 800;
    for (int k = t; k < 800; k += 256)
        orow[k] = (k < 775) ? f2bs(row[k]) : (u16)0;
}

// ---------------- GEMM: C[M,256] bf16 = A[M,K] @ Wt^T ----------------
template<bool AFP32>
__global__ __launch_bounds__(256) void gemm128(
        const void* __restrict__ Av, int lda, int M, int K,
        const u16* __restrict__ B, int ldb,
        u16* __restrict__ C, int ldc) {
    const float* Af = (const float*)Av;
    const u16*   Au = (const u16*)Av;
    __shared__ u16 Alds[128][40];
    __shared__ u16 Blds[128][40];
    const int t = threadIdx.x;
    const int row0 = blockIdx.x * 128, col0 = blockIdx.y * 128;
    const int wid = t >> 6, lane = t & 63;
    const int wm = wid >> 1, wn = wid & 1;
    const int quad = lane >> 4, l16 = lane & 15;

    f32x4 acc[4][4];
    f32x4 z = {0.f, 0.f, 0.f, 0.f};
    #pragma unroll
    for (int i = 0; i < 4; i++)
        #pragma unroll
        for (int j = 0; j < 4; j++) acc[i][j] = z;

    const int kTiles = (K + 31) >> 5;
    for (int kt = 0; kt < kTiles; ++kt) {
        const int k0 = kt << 5;
        #pragma unroll
        for (int c = 0; c < 2; c++) {
            int ch = t + c * 256;
            int r = ch >> 2, cp = (ch & 3) * 8;
            int gr = row0 + r;
            u16x8 v = {0,0,0,0,0,0,0,0};
            if (AFP32) {
                #pragma unroll
                for (int u = 0; u < 8; u++) {
                    int k = k0 + cp + u;
                    v[u] = (gr < M && k < K) ? f2bs(Af[(size_t)gr * lda + k]) : (u16)0;
                }
            } else {
                if (gr < M) v = *(const u16x8*)(Au + (size_t)gr * lda + k0 + cp);
            }
            *(u16x8*)&Alds[r][cp] = v;
        }
        #pragma unroll
        for (int c = 0; c < 2; c++) {
            int ch = t + c * 256;
            int r = ch >> 2, cp = (ch & 3) * 8;
            *(u16x8*)&Blds[r][cp] = *(const u16x8*)(B + (size_t)(col0 + r) * ldb + k0 + cp);
        }
        __syncthreads();
        bf16x8 af[4], bfr[4];
        #pragma unroll
        for (int it = 0; it < 4; it++) af[it] = *(const bf16x8*)&Alds[wm * 64 + it * 16 + l16][quad * 8];
        #pragma unroll
        for (int jt = 0; jt < 4; jt++) bfr[jt] = *(const bf16x8*)&Blds[wn * 64 + jt * 16 + l16][quad * 8];
        #pragma unroll
        for (int it = 0; it < 4; it++)
            #pragma unroll
            for (int jt = 0; jt < 4; jt++)
                acc[it][jt] = __builtin_amdgcn_mfma_f32_16x16x32_bf16(af[it], bfr[jt], acc[it][jt], 0, 0, 0);
        __syncthreads();
    }
    #pragma unroll
    for (int it = 0; it < 4; it++) {
        int gr0 = row0 + wm * 64 + it * 16 + quad * 4;
        #pragma unroll
        for (int jt = 0; jt < 4; jt++) {
            int gc = col0 + wn * 64 + jt * 16 + l16;
            #pragma unroll
            for (int r = 0; r < 4; r++) {
                int gr = gr0 + r;
                if (gr < M) C[(size_t)gr * ldc + gc] = f2bs(acc[it][jt][r]);
            }
        }
    }
}

// GEMM for layer3: C[M,32] fp32
__global__ __launch_bounds__(256) void gemm32(
        const u16* __restrict__ A, int lda, int M, int K,
        const u16* __restrict__ B, int ldb, float* __restrict__ C) {
    __shared__ u16 Alds[128][40];
    __shared__ u16 Blds[32][40];
    const int t = threadIdx.x;
    const int row0 = blockIdx.x * 128;
    const int wid = t >> 6, lane = t & 63;
    const int quad = lane >> 4, l16 = lane & 15;
    f32x4 acc[2][2];
    f32x4 z = {0.f, 0.f, 0.f, 0.f};
    acc[0][0] = z; acc[0][1] = z; acc[1][0] = z; acc[1][1] = z;
    const int kTiles = K >> 5;
    for (int kt = 0; kt < kTiles; ++kt) {
        const int k0 = kt << 5;
        #pragma unroll
        for (int c = 0; c < 2; c++) {
            int ch = t + c * 256;
            int r = ch >> 2, cp = (ch & 3) * 8;
            int gr = row0 + r;
            u16x8 v = {0,0,0,0,0,0,0,0};
            if (gr < M) v = *(const u16x8*)(A + (size_t)gr * lda + k0 + cp);
            *(u16x8*)&Alds[r][cp] = v;
        }
        if (t < 128) {
            int r = t >> 2, cp = (t & 3) * 8;
            *(u16x8*)&Blds[r][cp] = *(const u16x8*)(B + (size_t)r * ldb + k0 + cp);
        }
        __syncthreads();
        bf16x8 af[2], bfr[2];
        #pragma unroll
        for (int it = 0; it < 2; it++) af[it] = *(const bf16x8*)&Alds[wid * 32 + it * 16 + l16][quad * 8];
        #pragma unroll
        for (int jt = 0; jt < 2; jt++) bfr[jt] = *(const bf16x8*)&Blds[jt * 16 + l16][quad * 8];
        #pragma unroll
        for (int it = 0; it < 2; it++)
            #pragma unroll
            for (int jt = 0; jt < 2; jt++)
                acc[it][jt] = __builtin_amdgcn_mfma_f32_16x16x32_bf16(af[it], bfr[jt], acc[it][jt], 0, 0, 0);
        __syncthreads();
    }
    #pragma unroll
    for (int it = 0; it < 2; it++) {
        int gr0 = row0 + wid * 32 + it * 16 + quad * 4;
        #pragma unroll
        for (int jt = 0; jt < 2; jt++) {
            int gc = jt * 16 + l16;
            #pragma unroll
            for (int r = 0; r < 4; r++) {
                int gr = gr0 + r;
                if (gr < M) C[(size_t)gr * 32 + gc] = acc[it][jt][r];
            }
        }
    }
}

// ---------------- attention scalars ----------------
__global__ __launch_bounds__(256) void al_kernel(const u16* __restrict__ h,
        const float* __restrict__ a_s, const float* __restrict__ a_d,
        float* __restrict__ als, float* __restrict__ ald, int N) {
    int t = threadIdx.x;
    float as = a_s[t], ad = a_d[t];
    int base = blockIdx.x * 8;
    for (int u = 0; u < 8; u++) {
        int n = base + u;
        if (n >= N) return;
        float hv = bs2f(h[(size_t)n * 256 + t]);
        float ps = hv * as, pd = hv * ad;
        for (int off = 32; off >= 1; off >>= 1) { ps += __shfl_down(ps, off); pd += __shfl_down(pd, off); }
        if ((t & 63) == 0) { int w = t >> 6; als[n * 4 + w] = ps; ald[n * 4 + w] = pd; }
    }
}

__global__ __launch_bounds__(256) void al3_kernel(const float* __restrict__ h3,
        const float* __restrict__ a_s, const float* __restrict__ a_d,
        float* __restrict__ als, float* __restrict__ ald, int N) {
    int t = threadIdx.x, wid = t >> 6, lane = t & 63;
    int c = lane & 31, half = lane >> 5;
    float as = a_s[c], ad = a_d[c];
    int n = blockIdx.x * 8 + wid * 2 + half;
    if (n >= N) return;
    float hv = h3[(size_t)n * 32 + c];
    float ps = hv * as, pd = hv * ad;
    for (int off = 16; off >= 1; off >>= 1) { ps += __shfl_down(ps, off, 32); pd += __shfl_down(pd, off, 32); }
    if (c == 0) { als[n] = ps; ald[n] = pd; }
}

// ---------------- softmax prep, H=4: thread per node -> m[4], inv[4], aself[4] ----------
__global__ __launch_bounds__(256) void softprep4(const float* __restrict__ als,
        const float* __restrict__ ald, const int* __restrict__ ptr, const int* __restrict__ csr,
        float* __restrict__ minv, float* __restrict__ aself4, int N) {
    int n = blockIdx.x * 256 + threadIdx.x;
    if (n >= N) return;
    const int start = ptr[n], end = ptr[n + 1];
    const f32x4 adn = *(const f32x4*)&ald[(size_t)n * 4];
    const f32x4 asn = *(const f32x4*)&als[(size_t)n * 4];
    f32x4 es, m;
    #pragma unroll
    for (int h = 0; h < 4; h++) { es[h] = lrelu(asn[h] + adn[h]); m[h] = es[h]; }
    for (int j = start; j < end; j++) {
        const f32x4 a = *(const f32x4*)&als[(size_t)csr[j] * 4];
        #pragma unroll
        for (int h = 0; h < 4; h++) m[h] = fmaxf(m[h], lrelu(a[h] + adn[h]));
    }
    f32x4 sm;
    #pragma unroll
    for (int h = 0; h < 4; h++) sm[h] = expf(es[h] - m[h]);
    for (int j = start; j < end; j++) {
        const f32x4 a = *(const f32x4*)&als[(size_t)csr[j] * 4];
        #pragma unroll
        for (int h = 0; h < 4; h++) sm[h] += expf(lrelu(a[h] + adn[h]) - m[h]);
    }
    f32x4 inv, asf;
    #pragma unroll
    for (int h = 0; h < 4; h++) { inv[h] = 1.f / (sm[h] + 1e-16f); asf[h] = expf(es[h] - m[h]) * inv[h]; }
    *(f32x4*)&minv[(size_t)n * 8] = m;
    *(f32x4*)&minv[(size_t)n * 8 + 4] = inv;
    *(f32x4*)&aself4[(size_t)n * 4] = asf;
}

// ---------------- per-edge alpha, H=4: thread per edge ----------------
__global__ __launch_bounds__(256) void edge_alpha4(const float* __restrict__ als,
        const float* __restrict__ ald, const int* __restrict__ csr, const int* __restrict__ dstA,
        const float* __restrict__ minv, float* __restrict__ aew, int E) {
    int j = blockIdx.x * 256 + threadIdx.x;
    if (j >= E) return;
    const int s = csr[j], d = dstA[j];
    const f32x4 a   = *(const f32x4*)&als[(size_t)s * 4];
    const f32x4 adn = *(const f32x4*)&ald[(size_t)d * 4];
    const f32x4 m   = *(const f32x4*)&minv[(size_t)d * 8];
    const f32x4 inv = *(const f32x4*)&minv[(size_t)d * 8 + 4];
    f32x4 o;
    #pragma unroll
    for (int h = 0; h < 4; h++) o[h] = expf(lrelu(a[h] + adn[h]) - m[h]) * inv[h];
    *(f32x4*)&aew[(size_t)j * 4] = o;
}

// ---------------- gather (H=4, C=256 bf16): wave per node, 4x unrolled ----------------
__global__ __launch_bounds__(256) void agg_kernel(const u16* __restrict__ hbuf,
        const float* __restrict__ aew, const float* __restrict__ aself4,
        const int* __restrict__ ptr, const int* __restrict__ csr,
        const float* __restrict__ bias, u16* __restrict__ act, int N) {
    const int t = threadIdx.x, wid = t >> 6, lane = t & 63;
    const int i = blockIdx.x * 4 + wid;
    if (i >= N) return;
    const int start = ptr[i], end = ptr[i + 1];
    const int head = lane >> 4;

    const float asf = aself4[(size_t)i * 4 + head];
    const u16x4 hrs = *(const u16x4*)&hbuf[(size_t)i * 256 + lane * 4];
    f32x4 acc;
    #pragma unroll
    for (int c2 = 0; c2 < 4; c2++) acc[c2] = asf * bs2f(hrs[c2]);

    int j = start;
    for (; j + 4 <= end; j += 4) {
        int s0 = csr[j], s1 = csr[j + 1], s2 = csr[j + 2], s3 = csr[j + 3];
        float a0 = aew[(size_t)j * 4 + head];
        float a1 = aew[(size_t)(j + 1) * 4 + head];
        float a2 = aew[(size_t)(j + 2) * 4 + head];
        float a3 = aew[(size_t)(j + 3) * 4 + head];
        const u16x4 r0 = *(const u16x4*)&hbuf[(size_t)s0 * 256 + lane * 4];
        const u16x4 r1 = *(const u16x4*)&hbuf[(size_t)s1 * 256 + lane * 4];
        const u16x4 r2 = *(const u16x4*)&hbuf[(size_t)s2 * 256 + lane * 4];
        const u16x4 r3 = *(const u16x4*)&hbuf[(size_t)s3 * 256 + lane * 4];
        #pragma unroll
        for (int c2 = 0; c2 < 4; c2++) {
            acc[c2] = fmaf(a0, bs2f(r0[c2]), acc[c2]);
            acc[c2] = fmaf(a1, bs2f(r1[c2]), acc[c2]);
            acc[c2] = fmaf(a2, bs2f(r2[c2]), acc[c2]);
            acc[c2] = fmaf(a3, bs2f(r3[c2]), acc[c2]);
        }
    }
    for (; j < end; ++j) {
        int s = csr[j];
        float a = aew[(size_t)j * 4 + head];
        const u16x4 r = *(const u16x4*)&hbuf[(size_t)s * 256 + lane * 4];
        #pragma unroll
        for (int c2 = 0; c2 < 4; c2++) acc[c2] = fmaf(a, bs2f(r[c2]), acc[c2]);
    }

    const f32x4 bv = *(const f32x4*)&bias[lane * 4];
    u16x4 o;
    #pragma unroll
    for (int c2 = 0; c2 < 4; c2++) o[c2] = f2bs(fmaxf(acc[c2] + bv[c2], 0.f));
    *(u16x4*)&act[(size_t)i * 256 + lane * 4] = o;
}

// ---------------- softmax prep, H=1 ----------------
__global__ __launch_bounds__(256) void softprep1(const float* __restrict__ als,
        const float* __restrict__ ald, const int* __restrict__ ptr, const int* __restrict__ csr,
        float* __restrict__ m1, float* __restrict__ inv1, float* __restrict__ aself1, int N) {
    int n = blockIdx.x * 256 + threadIdx.x;
    if (n >= N) return;
    const int start = ptr[n], end = ptr[n + 1];
    const float adn = ald[n];
    const float e0 = lrelu(als[n] + adn);
    float m = e0;
    for (int j = start; j < end; j++) m = fmaxf(m, lrelu(als[csr[j]] + adn));
    float sm = expf(e0 - m);
    for (int j = start; j < end; j++) sm += expf(lrelu(als[csr[j]] + adn) - m);
    float inv = 1.f / (sm + 1e-16f);
    m1[n] = m; inv1[n] = inv; aself1[n] = expf(e0 - m) * inv;
}

__global__ __launch_bounds__(256) void edge_alpha1(const float* __restrict__ als,
        const float* __restrict__ ald, const int* __restrict__ csr, const int* __restrict__ dstA,
        const float* __restrict__ m1, const float* __restrict__ inv1,
        float* __restrict__ aew, int E) {
    int j = blockIdx.x * 256 + threadIdx.x;
    if (j >= E) return;
    const int s = csr[j], d = dstA[j];
    aew[j] = expf(lrelu(als[s] + ald[d]) - m1[d]) * inv1[d];
}

// ---------------- layer-3 gather fused with pool: edge-range blocks ----------------
// CSR is dst-sorted => graph-sorted. 8 edge-slots x 32 channels; register-accumulate
// while graph unchanged, flush via atomicAdd (rare).
__global__ __launch_bounds__(256) void agg3_edges(const float* __restrict__ h3,
        const float* __restrict__ aew, const int* __restrict__ csr, const int* __restrict__ gedge,
        float* __restrict__ pool, int E) {
    const int t = threadIdx.x, slot = t >> 5, c = t & 31;
    const int jend = min(blockIdx.x * 256 + 256, E);
    float acc = 0.f;
    int gcur = -1;
    for (int j = blockIdx.x * 256 + slot; j < jend; j += 8) {
        const int g = gedge[j];
        if (g != gcur) {
            if (gcur >= 0) atomicAdd(&pool[gcur * 32 + c], acc);
            acc = 0.f; gcur = g;
        }
        const int s = csr[j];
        acc = fmaf(aew[j], h3[(size_t)s * 32 + c], acc);
    }
    if (gcur >= 0) atomicAdd(&pool[gcur * 32 + c], acc);
}

// self-loop term + node count
__global__ __launch_bounds__(256) void self3(const float* __restrict__ h3,
        const float* __restrict__ aself1, const int* __restrict__ batch,
        float* __restrict__ pool, int* __restrict__ cnt, int N) {
    int idx = blockIdx.x * 256 + threadIdx.x;
    int n = idx >> 5, c = idx & 31;
    if (n >= N) return;
    int g = batch[n];
    atomicAdd(&pool[g * 32 + c], aself1[n] * h3[(size_t)n * 32 + c]);
    if (c == 0) atomicAdd(&cnt[g], 1);
}

__global__ void final_kernel(const float* __restrict__ pool, const int* __restrict__ cnt,
        const float* __restrict__ b3, float* __restrict__ out) {
    int idx = blockIdx.x * 256 + threadIdx.x;
    int g = idx >> 5, c = idx & 31;
    int n = cnt[g];
    out[idx] = (n > 0) ? (pool[idx] / (float)n + b3[c]) : 0.f;
}

extern "C" void kernel_launch(void* const* d_in, const int* in_sizes, int n_in,
                              void* d_out, int out_size, void* d_ws, size_t ws_size,
                              hipStream_t stream) {
    const int N = 50000, E = 800000, G = 512;
    const float* x    = (const float*)d_in[0];
    const int*   ei   = (const int*)d_in[1];
    const int*   batch= (const int*)d_in[2];
    const float* W1   = (const float*)d_in[3];
    const float* as1  = (const float*)d_in[4];
    const float* ad1  = (const float*)d_in[5];
    const float* b1   = (const float*)d_in[6];
    const float* W2   = (const float*)d_in[7];
    const float* as2  = (const float*)d_in[8];
    const float* ad2  = (const float*)d_in[9];
    const float* b2   = (const float*)d_in[10];
    const float* W3   = (const float*)d_in[11];
    const float* as3  = (const float*)d_in[12];
    const float* ad3  = (const float*)d_in[13];
    const float* b3   = (const float*)d_in[14];
    const int* esrc = ei;
    const int* edst = ei + E;

    char* base = (char*)d_ws; size_t off = 0;
    auto alloc = [&](size_t bytes) -> void* {
        void* p = base + off; off = (off + bytes + 255) & ~(size_t)255; return p;
    };
    u16*   hbuf = (u16*)  alloc((size_t)N * 256 * 2);
    u16*   act  = (u16*)  alloc((size_t)N * 256 * 2);
    float* h3   = (float*)alloc((size_t)N * 32 * 4);
    float* als  = (float*)alloc((size_t)N * 4 * 4);
    float* ald  = (float*)alloc((size_t)N * 4 * 4);
    float* minv = (float*)alloc((size_t)N * 8 * 4);
    float* aself= (float*)alloc((size_t)N * 4 * 4);
    float* aew  = (float*)alloc((size_t)E * 4 * 4);
    int*   deg  = (int*)  alloc((size_t)N * 4);
    int*   ptr  = (int*)  alloc((size_t)(N + 1) * 4);
    int*   cur  = (int*)  alloc((size_t)N * 4);
    int*   csr  = (int*)  alloc((size_t)E * 4);
    int*   dstA = (int*)  alloc((size_t)E * 4);
    int*   gedge= (int*)  alloc((size_t)E * 4);
    u16*   Wt   = (u16*)  alloc((size_t)256 * 800 * 2);
    int*   bsum = (int*)  alloc((size_t)64 * 4);
    float* pool = (float*)alloc((size_t)G * 32 * 4);
    int*   cnt  = (int*)  alloc((size_t)G * 4);
    u16*   xbf  = (u16*)  alloc((size_t)N * 800 * 2);   // optional fast path
    const bool use_xbf = (off <= ws_size);

    hipMemsetAsync(deg, 0, (size_t)N * 4, stream);
    hipMemsetAsync(pool, 0, (size_t)G * 32 * 4, stream);
    hipMemsetAsync(cnt, 0, (size_t)G * 4, stream);

    const int nb = (N + 1023) / 1024;
    deg_kernel<<<(E + 255) / 256, 256, 0, stream>>>(edst, deg, E);
    scan_local<<<nb, 1024, 0, stream>>>(deg, ptr, bsum, N);
    scan_carry<<<1, 64, 0, stream>>>(bsum, nb);
    scan_final<<<nb, 1024, 0, stream>>>(deg, ptr, cur, bsum, N);
    fill_kernel<<<(E + 255) / 256, 256, 0, stream>>>(esrc, edst, batch, cur, csr, dstA, gedge, E);

    dim3 g128((N + 127) / 128, 2);
    const int aggGrid = (N + 3) / 4;
    const int nodeGrid = (N + 255) / 256;
    const int edgeGrid = (E + 255) / 256;
    // ---- layer 1 ----
    transpose_w<<<(256 * 800 + 255) / 256, 256, 0, stream>>>(W1, Wt, 775, 256, 800);
    if (use_xbf) {
        conv_x<<<N, 256, 0, stream>>>(x, xbf);
        gemm128<false><<<g128, 256, 0, stream>>>(xbf, 800, N, 775, Wt, 800, hbuf, 256);
    } else {
        gemm128<true><<<g128, 256, 0, stream>>>(x, 775, N, 775, Wt, 800, hbuf, 256);
    }
    al_kernel<<<(N + 7) / 8, 256, 0, stream>>>(hbuf, as1, ad1, als, ald, N);
    softprep4<<<nodeGrid, 256, 0, stream>>>(als, ald, ptr, csr, minv, aself, N);
    edge_alpha4<<<edgeGrid, 256, 0, stream>>>(als, ald, csr, dstA, minv, aew, E);
    agg_kernel<<<aggGrid, 256, 0, stream>>>(hbuf, aew, aself, ptr, csr, b1, act, N);
    // ---- layer 2 ----
    transpose_w<<<(256 * 256 + 255) / 256, 256, 0, stream>>>(W2, Wt, 256, 256, 256);
    gemm128<false><<<g128, 256, 0, stream>>>(act, 256, N, 256, Wt, 256, hbuf, 256);
    al_kernel<<<(N + 7) / 8, 256, 0, stream>>>(hbuf, as2, ad2, als, ald, N);
    softprep4<<<nodeGrid, 256, 0, stream>>>(als, ald, ptr, csr, minv, aself, N);
    edge_alpha4<<<edgeGrid, 256, 0, stream>>>(als, ald, csr, dstA, minv, aew, E);
    agg_kernel<<<aggGrid, 256, 0, stream>>>(hbuf, aew, aself, ptr, csr, b2, act, N);
    // ---- layer 3 ----
    transpose_w<<<(32 * 256 + 255) / 256, 256, 0, stream>>>(W3, Wt, 256, 32, 256);
    gemm32<<<(N + 127) / 128, 256, 0, stream>>>(act, 256, N, 256, Wt, 256, h3);
    al3_kernel<<<(N + 7) / 8, 256, 0, stream>>>(h3, as3, ad3, als, ald, N);
    softprep1<<<nodeGrid, 256, 0, stream>>>(als, ald, ptr, csr, minv, minv + N, aself, N);
    edge_alpha1<<<edgeGrid, 256, 0, stream>>>(als, ald, csr, dstA, minv, minv + N, aew, E);
    agg3_edges<<<edgeGrid, 256, 0, stream>>>(h3, aew, csr, gedge, pool, E);
    self3<<<(N * 32 + 255) / 256, 256, 0, stream>>>(h3, aself, batch, pool, cnt, N);
    final_kernel<<<(G * 32 + 255) / 256, 256, 0, stream>>>(pool, cnt, b3, (float*)d_out);
}